// Round 1
// baseline (763.437 us; speedup 1.0000x reference)
//
#include <hip/hip_runtime.h>
#include <cstddef>
#include <cstdint>

#define NB 64
#define ND 1024
#define NO 31
#define NSTEPS 16

typedef _Float16 half8 __attribute__((ext_vector_type(8)));
typedef float floatx4 __attribute__((ext_vector_type(4)));

// ---------------- softmax over opcode logits: W[b][t][o] ----------------
__global__ void softmax_k(const float* __restrict__ logits, float* __restrict__ W) {
    int row = blockIdx.x * blockDim.x + threadIdx.x;  // row = b*16 + t
    if (row >= NB * NSTEPS) return;
    const float* x = logits + (size_t)row * NO;
    float m = -1e30f;
    for (int o = 0; o < NO; ++o) m = fmaxf(m, x[o]);
    float e[NO]; float s = 0.f;
    for (int o = 0; o < NO; ++o) { e[o] = expf(x[o] - m); s += e[o]; }
    float inv = 1.0f / s;
    float* wo = W + (size_t)row * NO;
    for (int o = 0; o < NO; ++o) wo[o] = e[o] * inv;
}

// ------------- convert+transpose: Kt[o][n][d] = (f16) K[o][d][n] -------------
__global__ void kconv_k(const float* __restrict__ K, _Float16* __restrict__ Kt) {
    __shared__ float tile[32][33];
    int o = blockIdx.z;
    int d0 = blockIdx.x * 32, n0 = blockIdx.y * 32;
    int t = threadIdx.x;
    int r = t >> 3, c = (t & 7) * 4;
    const float* src = K + ((size_t)o << 20) + (size_t)(d0 + r) * ND + n0 + c;
    float4 v = *(const float4*)src;
    tile[r][c + 0] = v.x; tile[r][c + 1] = v.y; tile[r][c + 2] = v.z; tile[r][c + 3] = v.w;
    __syncthreads();
    union { _Float16 h[4]; uint64_t u; } p;
    p.h[0] = (_Float16)tile[c + 0][r];
    p.h[1] = (_Float16)tile[c + 1][r];
    p.h[2] = (_Float16)tile[c + 2][r];
    p.h[3] = (_Float16)tile[c + 3][r];
    uint64_t* dst = (uint64_t*)(Kt + ((size_t)o << 20) + (size_t)(n0 + r) * ND + d0 + c);
    *dst = p.u;
}

// ---------------- GEMM: P[o][b][n0..n0+64) = (w[:,o]*h) @ K_o ----------------
// FAST: B from pre-transposed fp16 Kt[o][n][d]. Fallback: B from fp32 K[o][d][n].
template <bool FAST>
__global__ __launch_bounds__(256) void gemm_k(
    const float* __restrict__ h, const _Float16* __restrict__ Kt,
    const float* __restrict__ Kf32, const float* __restrict__ W,
    float* __restrict__ P, int step)
{
    int o  = blockIdx.y;
    int n0 = blockIdx.x * 64;
    __shared__ _Float16 lds_a[64][32];   // [b_row][d_local]
    __shared__ _Float16 lds_b[64][32];   // [n_local][d_local]
    int tid  = threadIdx.x;
    int lane = tid & 63, wid = tid >> 6;
    int row  = tid >> 2, c8 = (tid & 3) * 8;
    float wv = W[((size_t)row * NSTEPS + step) * NO + o];

    floatx4 acc[4] = { {0.f,0.f,0.f,0.f}, {0.f,0.f,0.f,0.f},
                       {0.f,0.f,0.f,0.f}, {0.f,0.f,0.f,0.f} };
    int fdl = tid >> 3, fnc = (tid & 7) * 8;   // fallback staging indices

    for (int d0 = 0; d0 < ND; d0 += 32) {
        // ---- stage A (w-scaled h, fp32 -> fp16) ----
        const float* hp = h + (size_t)row * ND + d0 + c8;
        float4 a0 = *(const float4*)hp;
        float4 a1 = *(const float4*)(hp + 4);
        half8 av;
        av[0] = (_Float16)(a0.x * wv); av[1] = (_Float16)(a0.y * wv);
        av[2] = (_Float16)(a0.z * wv); av[3] = (_Float16)(a0.w * wv);
        av[4] = (_Float16)(a1.x * wv); av[5] = (_Float16)(a1.y * wv);
        av[6] = (_Float16)(a1.z * wv); av[7] = (_Float16)(a1.w * wv);
        *(half8*)&lds_a[row][c8] = av;
        // ---- stage B ----
        if (FAST) {
            const _Float16* kp = Kt + ((size_t)o << 20) + (size_t)(n0 + row) * ND + d0 + c8;
            *(half8*)&lds_b[row][c8] = *(const half8*)kp;
        } else {
            const float* kp = Kf32 + ((size_t)o << 20) + (size_t)(d0 + fdl) * ND + n0 + fnc;
            float4 b0 = *(const float4*)kp;
            float4 b1 = *(const float4*)(kp + 4);
            lds_b[fnc + 0][fdl] = (_Float16)b0.x; lds_b[fnc + 1][fdl] = (_Float16)b0.y;
            lds_b[fnc + 2][fdl] = (_Float16)b0.z; lds_b[fnc + 3][fdl] = (_Float16)b0.w;
            lds_b[fnc + 4][fdl] = (_Float16)b1.x; lds_b[fnc + 5][fdl] = (_Float16)b1.y;
            lds_b[fnc + 6][fdl] = (_Float16)b1.z; lds_b[fnc + 7][fdl] = (_Float16)b1.w;
        }
        __syncthreads();
        // ---- MFMA: wave wid owns rows [16*wid, 16*wid+16) x all 64 cols ----
        int q = lane >> 4, ml = lane & 15;
        half8 af = *(half8*)&lds_a[wid * 16 + ml][q * 8];
        #pragma unroll
        for (int j = 0; j < 4; ++j) {
            half8 bf = *(half8*)&lds_b[j * 16 + ml][q * 8];
            acc[j] = __builtin_amdgcn_mfma_f32_16x16x32_f16(af, bf, acc[j], 0, 0, 0);
        }
        __syncthreads();
    }
    // ---- epilogue: C/D layout col=lane&15, row=(lane>>4)*4+r ----
    int q = lane >> 4, ml = lane & 15;
    float* Pp = P + ((size_t)o << 16);
    #pragma unroll
    for (int j = 0; j < 4; ++j) {
        #pragma unroll
        for (int r = 0; r < 4; ++r) {
            int bb  = wid * 16 + q * 4 + r;
            int col = n0 + j * 16 + ml;
            Pp[(size_t)bb * ND + col] = acc[j][r];
        }
    }
}

// -------- reduce partials over o + gated update: h_out = g*T + (1-g)*h --------
__global__ void update_k(const float* __restrict__ hin, const float* __restrict__ P,
                         const float* __restrict__ operands, float* __restrict__ hout,
                         int step)
{
    int idx = blockIdx.x * blockDim.x + threadIdx.x;  // float4 index
    int b = idx >> 8;
    int k = (idx & 255) * 4;
    float gl = operands[(size_t)b * 64 + step * 4 + 3];
    float g  = 1.0f / (1.0f + expf(-gl));
    float sx = 0.f, sy = 0.f, sz = 0.f, sw = 0.f;
    #pragma unroll 4
    for (int o = 0; o < NO; ++o) {
        float4 p = *(const float4*)(P + ((size_t)o << 16) + (size_t)b * ND + k);
        sx += p.x; sy += p.y; sz += p.z; sw += p.w;
    }
    float4 hv = *(const float4*)(hin + (size_t)b * ND + k);
    float4 outv;
    outv.x = g * sx + (1.f - g) * hv.x;
    outv.y = g * sy + (1.f - g) * hv.y;
    outv.z = g * sz + (1.f - g) * hv.z;
    outv.w = g * sw + (1.f - g) * hv.w;
    *(float4*)(hout + (size_t)b * ND + k) = outv;
}

extern "C" void kernel_launch(void* const* d_in, const int* in_sizes, int n_in,
                              void* d_out, int out_size, void* d_ws, size_t ws_size,
                              hipStream_t stream)
{
    const float* logits   = (const float*)d_in[0];  // (64,16,31)
    const float* operands = (const float*)d_in[1];  // (64,16,4)
    const float* signal   = (const float*)d_in[2];  // (64,1024)
    const float* opk      = (const float*)d_in[3];  // (31,1024,1024)
    float* out = (float*)d_out;
    char* ws = (char*)d_ws;

    size_t offW = 0;                                   // 128 KB for W
    size_t offP = 131072;                              // partials: 31*64*1024*4
    size_t offH = offP + (size_t)NO * NB * ND * 4;
    size_t offK = offH + 2ull * NB * ND * 4;           // two h buffers
    size_t need_fast = offK + (size_t)NO * ND * ND * 2;

    float*    W  = (float*)(ws + offW);
    float*    P  = (float*)(ws + offP);
    float*    h0 = (float*)(ws + offH);
    float*    h1 = h0 + NB * ND;
    _Float16* Kt = (_Float16*)(ws + offK);
    bool fast = (ws_size >= need_fast);

    softmax_k<<<dim3((NB * NSTEPS + 255) / 256), 256, 0, stream>>>(logits, W);
    if (fast) kconv_k<<<dim3(32, 32, NO), 256, 0, stream>>>(opk, Kt);

    const float* hc = signal;
    float* hn = h0;
    for (int t = 0; t < NSTEPS; ++t) {
        if (fast)
            gemm_k<true><<<dim3(16, NO), 256, 0, stream>>>(hc, Kt, nullptr, W, P, t);
        else
            gemm_k<false><<<dim3(16, NO), 256, 0, stream>>>(hc, nullptr, opk, W, P, t);
        float* dst = (t == NSTEPS - 1) ? out : hn;
        update_k<<<dim3(64), 256, 0, stream>>>(hc, P, operands, dst, t);
        hc = dst;
        hn = (hn == h0) ? h1 : h0;
    }
}

// Round 2
// 620.188 us; speedup vs baseline: 1.2310x; 1.2310x over previous
//
#include <hip/hip_runtime.h>
#include <cstddef>
#include <cstdint>

#define NB 64
#define ND 1024
#define NO 31
#define NSTEPS 16
#define KS 62            // k-splits (k-chunk = 512 k-units, never crosses an opcode)
#define KT32 992         // total K32 steps = 31*1024/32
#define KC32 16          // K32 steps per block

typedef _Float16 half8 __attribute__((ext_vector_type(8)));
typedef float floatx4 __attribute__((ext_vector_type(4)));

// ---------------- softmax over opcode logits: W[b][t][o] ----------------
__global__ void softmax_k(const float* __restrict__ logits, float* __restrict__ W) {
    int row = blockIdx.x * blockDim.x + threadIdx.x;  // row = b*16 + t
    if (row >= NB * NSTEPS) return;
    const float* x = logits + (size_t)row * NO;
    float m = -1e30f;
    for (int o = 0; o < NO; ++o) m = fmaxf(m, x[o]);
    float e[NO]; float s = 0.f;
    for (int o = 0; o < NO; ++o) { e[o] = expf(x[o] - m); s += e[o]; }
    float inv = 1.0f / s;
    float* wo = W + (size_t)row * NO;
    for (int o = 0; o < NO; ++o) wo[o] = e[o] * inv;
}

// ---- kconv: Ktf fragment-ordered fp16 B ----
// half8 unit index: (ns*KT32 + kt)*64 + l ; element j of that half8 =
//   B[k][n] with k = kt*32 + (l>>4)*8 + j, n = ns*16 + (l&15),
//   B[k][n] = K[o = k>>10][d = k&1023][n]
__global__ void kconv_k(const float* __restrict__ K, _Float16* __restrict__ Ktf) {
    int gid = blockIdx.x * 256 + threadIdx.x;   // total = 64*992*64 = 4,063,232
    int l  = gid & 63;
    int kt = (gid >> 6) % KT32;
    int ns = gid / (64 * KT32);
    int kbase = kt * 32 + (l >> 4) * 8;         // o constant across the 8 j's
    int n  = ns * 16 + (l & 15);
    int o  = kbase >> 10;
    int d0 = kbase & 1023;
    const float* src = K + ((size_t)o << 20) + (size_t)d0 * ND + n;
    half8 v;
    #pragma unroll
    for (int j = 0; j < 8; ++j) v[j] = (_Float16)src[(size_t)j * ND];
    *(half8*)(Ktf + (size_t)gid * 8) = v;
}

// ---- GEMM: P[ks][b][n] = sum over block's k-chunk of (w*h) @ B ----
// grid (8 n-tiles of 128, 62 k-splits), 256 thr. Wave = M64 x N32.
// A staged once per block into LDS, frag-ordered; B streamed global->reg.
__global__ __launch_bounds__(256) void gemm_k(
    const float* __restrict__ h, const _Float16* __restrict__ Ktf,
    const float* __restrict__ W, float* __restrict__ P, int step)
{
    __shared__ _Float16 lds_a[64 * 512];   // half8-index: p*64 + b  (p = s*4+q)
    int nb = blockIdx.x;                   // 0..7
    int ks = blockIdx.y;                   // 0..61
    int tid = threadIdx.x;
    int l = tid & 63, w = tid >> 6;
    int o = ks >> 1;
    int d_base = (ks & 1) * 512;

    // ---- stage A: fp32 h * w  ->  fp16, frag-ordered ----
    {
        int b = tid >> 2, u = tid & 3;
        float wv = W[((size_t)b * NSTEPS + step) * NO + o];
        const float* hb = h + (size_t)b * ND + d_base;
        #pragma unroll
        for (int li = 0; li < 16; ++li) {
            int p = li * 4 + u;                       // p = s*4+q, d offset = p*8
            float4 x0 = *(const float4*)(hb + p * 8);
            float4 x1 = *(const float4*)(hb + p * 8 + 4);
            half8 v;
            v[0] = (_Float16)(x0.x * wv); v[1] = (_Float16)(x0.y * wv);
            v[2] = (_Float16)(x0.z * wv); v[3] = (_Float16)(x0.w * wv);
            v[4] = (_Float16)(x1.x * wv); v[5] = (_Float16)(x1.y * wv);
            v[6] = (_Float16)(x1.z * wv); v[7] = (_Float16)(x1.w * wv);
            *(half8*)&lds_a[(size_t)(p * 64 + b) * 8] = v;
        }
    }
    __syncthreads();

    int ml = l & 15, q = l >> 4;
    int ns0 = nb * 8 + w * 2;                 // two n-subtiles of 16 per wave
    const half8* Bp0 = (const half8*)Ktf + ((size_t)ns0 * KT32 + (size_t)ks * KC32) * 64 + l;
    const half8* Bp1 = (const half8*)Ktf + ((size_t)(ns0 + 1) * KT32 + (size_t)ks * KC32) * 64 + l;
    const half8* Ap  = (const half8*)lds_a;

    floatx4 acc[2][4] = {};
    #pragma unroll 4
    for (int s = 0; s < KC32; ++s) {
        half8 b0 = Bp0[(size_t)s * 64];
        half8 b1 = Bp1[(size_t)s * 64];
        int abase = (s * 4 + q) * 64 + ml;
        half8 a0 = Ap[abase];
        half8 a1 = Ap[abase + 16];
        half8 a2 = Ap[abase + 32];
        half8 a3 = Ap[abase + 48];
        acc[0][0] = __builtin_amdgcn_mfma_f32_16x16x32_f16(a0, b0, acc[0][0], 0, 0, 0);
        acc[0][1] = __builtin_amdgcn_mfma_f32_16x16x32_f16(a1, b0, acc[0][1], 0, 0, 0);
        acc[0][2] = __builtin_amdgcn_mfma_f32_16x16x32_f16(a2, b0, acc[0][2], 0, 0, 0);
        acc[0][3] = __builtin_amdgcn_mfma_f32_16x16x32_f16(a3, b0, acc[0][3], 0, 0, 0);
        acc[1][0] = __builtin_amdgcn_mfma_f32_16x16x32_f16(a0, b1, acc[1][0], 0, 0, 0);
        acc[1][1] = __builtin_amdgcn_mfma_f32_16x16x32_f16(a1, b1, acc[1][1], 0, 0, 0);
        acc[1][2] = __builtin_amdgcn_mfma_f32_16x16x32_f16(a2, b1, acc[1][2], 0, 0, 0);
        acc[1][3] = __builtin_amdgcn_mfma_f32_16x16x32_f16(a3, b1, acc[1][3], 0, 0, 0);
    }

    // ---- epilogue: C/D col = l&15, row = (l>>4)*4 + r (verified mapping) ----
    float* Pks = P + (size_t)ks * (NB * ND);
    #pragma unroll
    for (int nsub = 0; nsub < 2; ++nsub) {
        int n = (ns0 + nsub) * 16 + ml;
        #pragma unroll
        for (int mt = 0; mt < 4; ++mt) {
            #pragma unroll
            for (int r = 0; r < 4; ++r) {
                int b = mt * 16 + q * 4 + r;
                Pks[(size_t)b * ND + n] = acc[nsub][mt][r];
            }
        }
    }
}

// ---- reduce KS partials + gated update ----
__global__ void update_k(const float* __restrict__ hin, const float* __restrict__ P,
                         const float* __restrict__ operands, float* __restrict__ hout,
                         int step)
{
    int idx = blockIdx.x * blockDim.x + threadIdx.x;   // 65536 threads, 1 float each
    int b = idx >> 10, n = idx & 1023;
    float gl = operands[((size_t)b * NSTEPS + step) * 4 + 3];
    float g  = 1.0f / (1.0f + expf(-gl));
    const float* p = P + (size_t)b * ND + n;
    float s0 = 0.f, s1 = 0.f;
    #pragma unroll 2
    for (int ks = 0; ks < KS; ks += 2) {
        s0 += p[(size_t)ks * (NB * ND)];
        s1 += p[(size_t)(ks + 1) * (NB * ND)];
    }
    float hv = hin[idx];
    hout[idx] = g * (s0 + s1) + (1.0f - g) * hv;
}

extern "C" void kernel_launch(void* const* d_in, const int* in_sizes, int n_in,
                              void* d_out, int out_size, void* d_ws, size_t ws_size,
                              hipStream_t stream)
{
    const float* logits   = (const float*)d_in[0];  // (64,16,31)
    const float* operands = (const float*)d_in[1];  // (64,16,4)
    const float* signal   = (const float*)d_in[2];  // (64,1024)
    const float* opk      = (const float*)d_in[3];  // (31,1024,1024)
    float* out = (float*)d_out;
    char* ws = (char*)d_ws;

    size_t offW = 0;                                   // 128 KB
    size_t offP = 131072;                              // KS*64*1024*4 = 15.5 MB
    size_t offH = offP + (size_t)KS * NB * ND * 4;
    size_t offK = offH + 2ull * NB * ND * 4;           // Ktf: 62 MB fp16

    float*    W  = (float*)(ws + offW);
    float*    P  = (float*)(ws + offP);
    float*    h0 = (float*)(ws + offH);
    float*    h1 = h0 + NB * ND;
    _Float16* Ktf = (_Float16*)(ws + offK);

    softmax_k<<<dim3(4), 256, 0, stream>>>(logits, W);
    kconv_k<<<dim3(15872), 256, 0, stream>>>(opk, Ktf);

    const float* hc = signal;
    float* hn = h0;
    for (int t = 0; t < NSTEPS; ++t) {
        gemm_k<<<dim3(8, KS), 256, 0, stream>>>(hc, Ktf, W, P, t);
        float* dst = (t == NSTEPS - 1) ? out : hn;
        update_k<<<dim3(256), 256, 0, stream>>>(hc, P, operands, dst, t);
        hc = dst;
        hn = (hn == h0) ? h1 : h0;
    }
}